// Round 20
// baseline (36.581 us; speedup 1.0000x reference)
//
#include <hip/hip_runtime.h>
#include <hip/hip_bf16.h>

#define N_SIDE 14
#define N_PATCH (N_SIDE * N_SIDE)   // 196
#define D_BB 384
#define DQ_BB (D_BB / 4)             // 96 float4 per cell
#define D_MODEL 512
#define BT_TOTAL 2048
#define LN_EPS 1e-5f
#define KSTEPS (D_BB / 32)           // 12 MFMA K-steps
#define PGR 5                        // pool cell groups (480 of 512 threads)
#define ALDS_P 392                   // padded LDS row (shorts): 784 B stride

typedef __attribute__((ext_vector_type(8))) short bf16x8;
typedef __attribute__((ext_vector_type(4))) float f32x4;

__device__ __forceinline__ unsigned short f2b(float f) {
    unsigned u = __float_as_uint(f);
    return (unsigned short)((u + 0x7FFFu + ((u >> 16) & 1u)) >> 16);
}

__device__ __forceinline__ void add4(float4& a, const float4& b) {
    a.x += b.x; a.y += b.y; a.z += b.z; a.w += b.w;
}

__device__ __forceinline__ void box_params(const float* __restrict__ bboxes, int bt,
                                           int& x1, int& y1, int& wd, int& total) {
    const float bx1 = bboxes[bt * 4 + 0];
    const float by1 = bboxes[bt * 4 + 1];
    const float bx2 = bboxes[bt * 4 + 2];
    const float by2 = bboxes[bt * 4 + 3];
    // match reference exactly: clip -> trunc/ceil -> clip -> max
    x1 = (int)fminf(fmaxf(bx1 * (float)N_SIDE, 0.f), (float)(N_SIDE - 1));
    y1 = (int)fminf(fmaxf(by1 * (float)N_SIDE, 0.f), (float)(N_SIDE - 1));
    int x2 = (int)fminf(fmaxf(ceilf(fminf(fmaxf(bx2 * (float)N_SIDE, 0.f), (float)N_SIDE)), 1.f), (float)N_SIDE);
    int y2 = (int)fminf(fmaxf(ceilf(fminf(fmaxf(by2 * (float)N_SIDE, 0.f), (float)N_SIDE)), 1.f), (float)N_SIDE);
    x2 = max(x2, x1 + 1);
    y2 = max(y2, y1 + 1);
    wd = x2 - x1;
    total = wd * (y2 - y1);
}

// ---------------- Kernel A: W pack (tiny, runs first) ----------------
// grid = 64 x 192. Packs W into MFMA B-fragment order: wpack[nt][ks][lane][8].
__global__ __launch_bounds__(192) void wpack_kernel(
    const float* __restrict__ W,            // [384,512]
    unsigned short* __restrict__ wpack)     // [32][12][64][8]
{
    const int bid  = blockIdx.x;
    const int t    = threadIdx.x;
    const int nt   = bid >> 1;
    const int kh   = bid & 1;
    const int lane = t & 63;
    const int w3   = t >> 6;       // 0..2
#pragma unroll
    for (int u = 0; u < 4; ++u) {
        const int grp = w3 * 4 + u;    // 0..11
        const int ksl = grp >> 1;      // 0..5
        const int jh  = grp & 1;
        const int ks  = kh * 6 + ksl;  // 0..11
        const int n   = nt * 16 + (lane & 15);
        const int kb  = ks * 32 + (lane >> 4) * 8 + jh * 4;
        ushort4 w4;
        w4.x = f2b(W[(size_t)(kb + 0) * D_MODEL + n]);
        w4.y = f2b(W[(size_t)(kb + 1) * D_MODEL + n]);
        w4.z = f2b(W[(size_t)(kb + 2) * D_MODEL + n]);
        w4.w = f2b(W[(size_t)(kb + 3) * D_MODEL + n]);
        *(ushort4*)(wpack + ((size_t)(nt * KSTEPS + ks) * 64 + lane) * 8 + jh * 4) = w4;
    }
}

// ---------------- Kernel B: fused pool(4 rows) + MFMA GEMM + LN + blend ----------------
// grid = 512 blocks x 512 thr (2 blocks/CU co-resident). Block pools its 4 bt rows
// into LDS (bf16, rows 4..15 zero), then its 8 waves run the R16 MFMA schedule
// (zero-padded A rows), LN over 512 cols, vis blend, store. The per-block gemm
// overlaps the CU-mate's pool phase.
__global__ __launch_bounds__(512) void fused_kernel(
    const float* __restrict__ patch,     // [BT,196,384]
    const float* __restrict__ bboxes,    // [BT,4]
    const unsigned short* __restrict__ wpack, // [32][12][64][8]
    const float* __restrict__ bias,      // [512]
    const float* __restrict__ gamma,     // [512]
    const float* __restrict__ beta,      // [512]
    const float* __restrict__ mask_tok,  // [512]
    const float* __restrict__ vis,       // [BT]
    float* __restrict__ out)             // [BT,512]
{
    const int tid = threadIdx.x;
    const int r0  = blockIdx.x * 4;
    const int qd  = tid % DQ_BB;   // 0..95
    const int g   = tid / DQ_BB;   // 0..5 (group 5 = 32 spare threads, idle in pool)

    __shared__ int            off_tab[N_PATCH];
    __shared__ float4         part[PGR][DQ_BB];        // 7.5 KB
    __shared__ unsigned short alds[16][ALDS_P];        // 12.25 KB (padded rows)
    __shared__ float          lns[8][16][2];           // 1 KB

    // ---- zero the A-tile (rows 4..15 stay zero; rows 0..3 overwritten by pool) ----
    {
        ushort4 z; z.x = z.y = z.z = z.w = 0;
        ushort4* a4 = (ushort4*)alds;
        for (int i = tid; i < 16 * (ALDS_P / 4); i += 512) a4[i] = z;
    }

    // ---- pool 4 rows ----
    for (int r = 0; r < 4; ++r) {
        int x1, y1, wd, total;
        box_params(bboxes, r0 + r, x1, y1, wd, total);
        const float inv_wd    = 1.f / (float)wd;
        const float inv_count = 1.f / (float)total;
        const int   cell0     = y1 * N_SIDE + x1;

        __syncthreads();   // off_tab/part reuse barrier (also covers alds zeroing, r==0)
        if (tid < total) {
            const int y = (int)(((float)tid + 0.5f) * inv_wd);  // exact for wd<=14
            const int x = tid - y * wd;
            off_tab[tid] = (cell0 + y * N_SIDE + x) * (D_BB * 4);   // byte offset
        }
        __syncthreads();

        if (tid < PGR * DQ_BB) {
            const char* __restrict__ basep =
                (const char*)patch + (size_t)(r0 + r) * N_PATCH * D_BB * 4 + (size_t)qd * 16;
            float4 acc = make_float4(0.f, 0.f, 0.f, 0.f);
            int c = g;
            for (; c + 3 * PGR < total; c += 4 * PGR) {
                const int o0 = off_tab[c];
                const int o1 = off_tab[c + PGR];
                const int o2 = off_tab[c + 2 * PGR];
                const int o3 = off_tab[c + 3 * PGR];
                const float4 v0 = *(const float4*)(basep + o0);
                const float4 v1 = *(const float4*)(basep + o1);
                const float4 v2 = *(const float4*)(basep + o2);
                const float4 v3 = *(const float4*)(basep + o3);
                acc.x += (v0.x + v1.x) + (v2.x + v3.x);
                acc.y += (v0.y + v1.y) + (v2.y + v3.y);
                acc.z += (v0.z + v1.z) + (v2.z + v3.z);
                acc.w += (v0.w + v1.w) + (v2.w + v3.w);
            }
            for (; c < total; c += PGR) {
                const float4 v = *(const float4*)(basep + off_tab[c]);
                acc.x += v.x; acc.y += v.y; acc.z += v.z; acc.w += v.w;
            }
            part[g][qd] = acc;
        }
        __syncthreads();

        if (tid < DQ_BB) {
            float4 s = part[0][tid];
#pragma unroll
            for (int p = 1; p < PGR; ++p) add4(s, part[p][tid]);
            ushort4 o;
            o.x = f2b(s.x * inv_count);
            o.y = f2b(s.y * inv_count);
            o.z = f2b(s.z * inv_count);
            o.w = f2b(s.w * inv_count);
            *(ushort4*)&alds[r][tid * 4] = o;
        }
    }
    __syncthreads();

    // ---- MFMA phase: 8 waves, each 4 n-tiles (R16 schedule; A rows 4..15 = 0) ----
    const int ch     = tid >> 6;     // 0..7
    const int lane   = tid & 63;
    const int lane_m = lane & 15;
    const int lane_g = lane >> 4;

    bf16x8 afrag[KSTEPS];
#pragma unroll
    for (int ks = 0; ks < KSTEPS; ++ks)
        afrag[ks] = *(const bf16x8*)&alds[lane_m][ks * 32 + lane_g * 8];

    f32x4 acc[4];
#pragma unroll
    for (int nt = 0; nt < 4; ++nt) acc[nt] = (f32x4){0.f, 0.f, 0.f, 0.f};

#pragma unroll
    for (int nt = 0; nt < 4; ++nt) {
        const unsigned short* bp = wpack + ((size_t)((ch * 4 + nt) * KSTEPS) * 64 + lane) * 8;
#pragma unroll
        for (int ks = 0; ks < KSTEPS; ++ks) {
            const bf16x8 b = *(const bf16x8*)(bp + (size_t)ks * 64 * 8);
            acc[nt] = __builtin_amdgcn_mfma_f32_16x16x32_bf16(afrag[ks], b, acc[nt], 0, 0, 0);
        }
    }

    // ---- bias + LN partials (rows m = lane_g*4+r; only m<4 are real) ----
    float s[4] = {0.f, 0.f, 0.f, 0.f}, s2[4] = {0.f, 0.f, 0.f, 0.f};
#pragma unroll
    for (int nt = 0; nt < 4; ++nt) {
        const float bs = bias[ch * 64 + nt * 16 + lane_m];
#pragma unroll
        for (int r = 0; r < 4; ++r) {
            const float v = acc[nt][r] + bs;
            acc[nt][r] = v;
            s[r] += v; s2[r] += v * v;
        }
    }
#pragma unroll
    for (int off = 1; off < 16; off <<= 1) {
#pragma unroll
        for (int r = 0; r < 4; ++r) {
            s[r]  += __shfl_xor(s[r],  off);
            s2[r] += __shfl_xor(s2[r], off);
        }
    }
    if (lane_m == 0) {
#pragma unroll
        for (int r = 0; r < 4; ++r) {
            lns[ch][lane_g * 4 + r][0] = s[r];
            lns[ch][lane_g * 4 + r][1] = s2[r];
        }
    }
    __syncthreads();

    // ---- stats + normalize + blend + store (real rows: lane_g==0, m = r) ----
    if (lane_g == 0) {
        float mean4[4], rstd4[4], v4[4], iv4[4];
#pragma unroll
        for (int r = 0; r < 4; ++r) {
            float S = 0.f, S2 = 0.f;
#pragma unroll
            for (int c = 0; c < 8; ++c) { S += lns[c][r][0]; S2 += lns[c][r][1]; }
            const float mean = S * (1.f / (float)D_MODEL);
            const float var  = S2 * (1.f / (float)D_MODEL) - mean * mean;
            mean4[r] = mean;
            rstd4[r] = rsqrtf(var + LN_EPS);
            const float v = vis[r0 + r];
            v4[r] = v; iv4[r] = 1.f - v;
        }
#pragma unroll
        for (int nt = 0; nt < 4; ++nt) {
            const int n = ch * 64 + nt * 16 + lane_m;
            const float gm  = gamma[n];
            const float bt_ = beta[n];
            const float mt  = mask_tok[n];
#pragma unroll
            for (int r = 0; r < 4; ++r) {
                const float o = v4[r] * ((acc[nt][r] - mean4[r]) * rstd4[r] * gm + bt_) + iv4[r] * mt;
                out[(size_t)(r0 + r) * D_MODEL + n] = o;
            }
        }
    }
}

extern "C" void kernel_launch(void* const* d_in, const int* in_sizes, int n_in,
                              void* d_out, int out_size, void* d_ws, size_t ws_size,
                              hipStream_t stream) {
    const float* patch  = (const float*)d_in[0];  // [2048,196,384]
    const float* bboxes = (const float*)d_in[1];  // [2048,4]
    const float* vis    = (const float*)d_in[2];  // [2048]
    // d_in[3] = B, d_in[4] = T (scalars, unused)
    const float* W      = (const float*)d_in[5];  // [384,512]
    const float* bias   = (const float*)d_in[6];  // [512]
    const float* gamma  = (const float*)d_in[7];  // [512]
    const float* beta   = (const float*)d_in[8];  // [512]
    const float* mtok   = (const float*)d_in[9];  // [1,512]

    unsigned short* wpack = (unsigned short*)d_ws;   // 384 KB
    float* out = (float*)d_out;

    wpack_kernel<<<64, 192, 0, stream>>>(W, wpack);
    fused_kernel<<<BT_TOTAL / 4, 512, 0, stream>>>(
        patch, bboxes, wpack, bias, gamma, beta, mtok, vis, out);
}